// Round 1
// baseline (1008.852 us; speedup 1.0000x reference)
//
#include <hip/hip_runtime.h>
#include <math.h>

static constexpr int N_NODES = 50000;
static constexpr int N_EDGES = 800000;
static constexpr int DMODEL  = 128;

// ---------------------------------------------------------------------------
// Tiled fp32 GEMM: C[M,DOUT] = A[M,DK] @ W[DK,DOUT] (+bias) (+res) (relu)
// BM=128, BN=64, BK=16, 256 threads, 8x4 micro-tile per thread.
// EPI: 0 = bias only (bias may be null), 1 = bias+relu, 2 = bias+residual
// NOTE: res/C may alias (in-place residual update) -> no __restrict__ there.
// ---------------------------------------------------------------------------
template<int DK, int DOUT, int EPI>
__global__ __launch_bounds__(256)
void gemm_kernel(const float* __restrict__ A, const float* __restrict__ W,
                 const float* __restrict__ bias, const float* res,
                 float* C, int M)
{
    __shared__ float As[16][132];   // [k][m], padded: store conflicts 2-way (free)
    __shared__ float Bs[16][64];    // [k][n]

    const int t  = threadIdx.x;
    const int tx = t & 15;
    const int ty = t >> 4;
    const int mBase = blockIdx.x * 128;
    const int nBase = blockIdx.y * 64;

    float acc[8][4];
#pragma unroll
    for (int i = 0; i < 8; ++i)
#pragma unroll
        for (int j = 0; j < 4; ++j) acc[i][j] = 0.f;

    for (int k0 = 0; k0 < DK; k0 += 16) {
        // stage A tile: 128 rows x 16 k  (512 float4, 2 per thread)
#pragma unroll
        for (int rep = 0; rep < 2; ++rep) {
            int idx = t + rep * 256;
            int row = idx >> 2;
            int kc  = (idx & 3) * 4;
            int gr  = mBase + row;
            float4 a4 = make_float4(0.f, 0.f, 0.f, 0.f);
            if (gr < M) a4 = *(const float4*)(A + (size_t)gr * DK + k0 + kc);
            As[kc + 0][row] = a4.x;
            As[kc + 1][row] = a4.y;
            As[kc + 2][row] = a4.z;
            As[kc + 3][row] = a4.w;
        }
        // stage B tile: 16 k x 64 n (256 float4, 1 per thread)
        {
            int kr = t >> 4;
            int nc = (t & 15) * 4;
            *(float4*)&Bs[kr][nc] =
                *(const float4*)(W + (size_t)(k0 + kr) * DOUT + nBase + nc);
        }
        __syncthreads();
#pragma unroll
        for (int kk = 0; kk < 16; ++kk) {
            float4 b4 = *(const float4*)&Bs[kk][tx * 4];
            float4 a0 = *(const float4*)&As[kk][ty * 8];
            float4 a1 = *(const float4*)&As[kk][ty * 8 + 4];
            float av[8] = {a0.x, a0.y, a0.z, a0.w, a1.x, a1.y, a1.z, a1.w};
            float bv[4] = {b4.x, b4.y, b4.z, b4.w};
#pragma unroll
            for (int i = 0; i < 8; ++i)
#pragma unroll
                for (int j = 0; j < 4; ++j)
                    acc[i][j] = fmaf(av[i], bv[j], acc[i][j]);
        }
        __syncthreads();
    }

    float bb[4] = {0.f, 0.f, 0.f, 0.f};
    if (bias) {
#pragma unroll
        for (int j = 0; j < 4; ++j) bb[j] = bias[nBase + tx * 4 + j];
    }
#pragma unroll
    for (int i = 0; i < 8; ++i) {
        int gr = mBase + ty * 8 + i;
        if (gr < M) {
            float o0 = acc[i][0] + bb[0];
            float o1 = acc[i][1] + bb[1];
            float o2 = acc[i][2] + bb[2];
            float o3 = acc[i][3] + bb[3];
            if (EPI == 2) {
                float4 r = *(const float4*)(res + (size_t)gr * DOUT + nBase + tx * 4);
                o0 += r.x; o1 += r.y; o2 += r.z; o3 += r.w;
            }
            if (EPI == 1) {
                o0 = fmaxf(o0, 0.f); o1 = fmaxf(o1, 0.f);
                o2 = fmaxf(o2, 0.f); o3 = fmaxf(o3, 0.f);
            }
            float4 o = make_float4(o0, o1, o2, o3);
            *(float4*)(C + (size_t)gr * DOUT + nBase + tx * 4) = o;
        }
    }
}

// ---------------------------------------------------------------------------
// LayerNorm over rows of [M,128]; in-place safe (each wave owns its row).
// ---------------------------------------------------------------------------
__global__ __launch_bounds__(256)
void ln_kernel(const float* x, const float* __restrict__ w,
               const float* __restrict__ b, float* out, int M)
{
    int row  = (int)((blockIdx.x * 256 + threadIdx.x) >> 6);
    int lane = threadIdx.x & 63;
    if (row >= M) return;
    const float* xr = x + (size_t)row * 128;
    float x0 = xr[lane];
    float x1 = xr[lane + 64];
    float s  = x0 + x1;
    float ss = x0 * x0 + x1 * x1;
#pragma unroll
    for (int o = 1; o < 64; o <<= 1) {
        s  += __shfl_xor(s, o, 64);
        ss += __shfl_xor(ss, o, 64);
    }
    float m   = s * (1.0f / 128.0f);
    float var = ss * (1.0f / 128.0f) - m * m;
    float rs  = rsqrtf(var + 1e-5f);
    out[(size_t)row * 128 + lane]      = (x0 - m) * rs * w[lane] + b[lane];
    out[(size_t)row * 128 + lane + 64] = (x1 - m) * rs * w[lane + 64] + b[lane + 64];
}

// ---------------------------------------------------------------------------
// CSR build: histogram -> scan (3 kernels) -> scatter (offsets used as cursor)
// Post-scatter: offsets[d] == end of segment d; beg(d) = d ? offsets[d-1] : 0.
// ---------------------------------------------------------------------------
__global__ void hist_kernel(const int* __restrict__ dst, int* counts, int E)
{
    int e = blockIdx.x * 256 + threadIdx.x;
    if (e < E) atomicAdd(&counts[dst[e]], 1);
}

__global__ __launch_bounds__(1024)
void scan1_kernel(const int* __restrict__ counts, int* offsets, int* blockSums, int N)
{
    __shared__ int sm[1024];
    int t = threadIdx.x;
    int i = blockIdx.x * 1024 + t;
    sm[t] = (i < N) ? counts[i] : 0;
    __syncthreads();
#pragma unroll
    for (int o = 1; o < 1024; o <<= 1) {
        int v = (t >= o) ? sm[t - o] : 0;
        __syncthreads();
        sm[t] += v;
        __syncthreads();
    }
    if (i < N) offsets[i + 1] = sm[t];
    if (t == 1023) blockSums[blockIdx.x] = sm[t];
}

__global__ void scan2_kernel(int* blockSums, int nb)
{
    int t = threadIdx.x;   // 64 threads = 1 wave
    int own = (t < nb) ? blockSums[t] : 0;
    int x = own;
#pragma unroll
    for (int o = 1; o < 64; o <<= 1) {
        int v = __shfl_up(x, o, 64);
        if (t >= o) x += v;
    }
    if (t < nb) blockSums[t] = x - own;   // exclusive
}

__global__ __launch_bounds__(1024)
void scan3_kernel(int* offsets, const int* __restrict__ blockSums, int N)
{
    int i = blockIdx.x * 1024 + threadIdx.x;
    if (i < N) offsets[i + 1] += blockSums[blockIdx.x];
    if (i == 0) offsets[0] = 0;
}

__global__ void scatter_kernel(const int* __restrict__ src, const int* __restrict__ dst,
                               int* offsets, int* esrc, int E)
{
    int e = blockIdx.x * 256 + threadIdx.x;
    if (e < E) {
        int d = dst[e];
        int pos = atomicAdd(&offsets[d], 1);
        esrc[pos] = src[e];
    }
}

// ---------------------------------------------------------------------------
// Attention aggregation: one wave per dst node. Lane covers dims {2l, 2l+1};
// head = lane>>3 -> per-head dot via 8-lane shuffle reduce.
// attn may alias q (row n is read by wave n only, written by wave n only).
// ---------------------------------------------------------------------------
__global__ __launch_bounds__(256)
void agg_kernel(const float* qv, const float* __restrict__ kv,
                const float* __restrict__ vv, const int* __restrict__ offsets,
                const int* __restrict__ esrc, float* attn, int n_nodes)
{
    int w    = (int)((blockIdx.x * 256 + threadIdx.x) >> 6);
    int lane = threadIdx.x & 63;
    if (w >= n_nodes) return;
    float2 q2 = *(const float2*)(qv + (size_t)w * 128 + lane * 2);
    int beg = (w == 0) ? 0 : offsets[w - 1];
    int end = offsets[w];
    float accx = 0.f, accy = 0.f, z = 0.f;
    for (int e = beg; e < end; ++e) {
        int s = esrc[e];
        float2 k2 = *(const float2*)(kv + (size_t)s * 128 + lane * 2);
        float2 v2 = *(const float2*)(vv + (size_t)s * 128 + lane * 2);
        float p = k2.x * q2.x + k2.y * q2.y;
        p += __shfl_xor(p, 1, 8);
        p += __shfl_xor(p, 2, 8);
        p += __shfl_xor(p, 4, 8);
        p *= 0.25f;                          // 1/sqrt(16)
        p = fminf(fmaxf(p, -5.f), 5.f);
        float sv = __expf(p);
        accx = fmaf(sv, v2.x, accx);
        accy = fmaf(sv, v2.y, accy);
        z += sv;
    }
    float inv = 1.f / (z + 1e-6f);
    *(float2*)(attn + (size_t)w * 128 + lane * 2) = make_float2(accx * inv, accy * inv);
}

// ---------------------------------------------------------------------------
extern "C" void kernel_launch(void* const* d_in, const int* in_sizes, int n_in,
                              void* d_out, int out_size, void* d_ws, size_t ws_size,
                              hipStream_t stream)
{
    const float* h_in  = (const float*)d_in[0];
    const int*   src   = (const int*)d_in[1];
    const int*   dst   = (const int*)d_in[2];
    const float* W_emb = (const float*)d_in[3];
    const float* Wq    = (const float*)d_in[4];
    const float* bq    = (const float*)d_in[5];
    const float* Wk    = (const float*)d_in[6];
    const float* bk    = (const float*)d_in[7];
    const float* Wv    = (const float*)d_in[8];
    const float* bv    = (const float*)d_in[9];
    const float* Wo    = (const float*)d_in[10];
    const float* bo    = (const float*)d_in[11];
    const float* ln1w  = (const float*)d_in[12];
    const float* ln1b  = (const float*)d_in[13];
    const float* Wf1   = (const float*)d_in[14];
    const float* bf1   = (const float*)d_in[15];
    const float* Wf2   = (const float*)d_in[16];
    const float* bf2   = (const float*)d_in[17];
    const float* ln2w  = (const float*)d_in[18];
    const float* ln2b  = (const float*)d_in[19];
    float* out = (float*)d_out;

    const int N = N_NODES, E = N_EDGES;
    const size_t NF = (size_t)N * DMODEL;   // 6.4M floats

    // workspace carve (~106 MB)
    float* hbuf = (float*)d_ws;
    float* qbuf = hbuf + NF;      // also: attn, and f1 spans qbuf..kbuf (N x 256)
    float* kbuf = qbuf + NF;
    float* vbuf = kbuf + NF;
    int* offsets   = (int*)(vbuf + NF);       // N+1
    int* blockSums = offsets + (N + 1);       // 64
    int* counts    = blockSums + 64;          // N
    int* esrc      = counts + N;              // E

    const int edgeBlocks = (E + 255) / 256;     // 3125
    const int scanBlocks = (N + 1023) / 1024;   // 49
    const int rowBlocks  = (N + 3) / 4;         // 12500 (4 waves/block)
    dim3 g128((N + 127) / 128, 2);              // DOUT=128
    dim3 g256((N + 127) / 128, 4);              // DOUT=256

    // ---- CSR build ----
    hipMemsetAsync(counts, 0, (size_t)N * sizeof(int), stream);
    hist_kernel<<<edgeBlocks, 256, 0, stream>>>(dst, counts, E);
    scan1_kernel<<<scanBlocks, 1024, 0, stream>>>(counts, offsets, blockSums, N);
    scan2_kernel<<<1, 64, 0, stream>>>(blockSums, scanBlocks);
    scan3_kernel<<<scanBlocks, 1024, 0, stream>>>(offsets, blockSums, N);
    scatter_kernel<<<edgeBlocks, 256, 0, stream>>>(src, dst, offsets, esrc, E);

    // ---- embedding: h = h_in @ W_emb ----
    gemm_kernel<128, 128, 0><<<g128, 256, 0, stream>>>(h_in, W_emb, nullptr, nullptr, hbuf, N);

    for (int l = 0; l < 2; ++l) {
        const float* Wq_l = Wq + (size_t)l * 128 * 128;
        const float* Wk_l = Wk + (size_t)l * 128 * 128;
        const float* Wv_l = Wv + (size_t)l * 128 * 128;
        const float* Wo_l = Wo + (size_t)l * 128 * 128;
        const float* Wf1_l = Wf1 + (size_t)l * 128 * 256;
        const float* Wf2_l = Wf2 + (size_t)l * 256 * 128;

        gemm_kernel<128, 128, 0><<<g128, 256, 0, stream>>>(hbuf, Wq_l, bq + l * 128, nullptr, qbuf, N);
        gemm_kernel<128, 128, 0><<<g128, 256, 0, stream>>>(hbuf, Wk_l, bk + l * 128, nullptr, kbuf, N);
        gemm_kernel<128, 128, 0><<<g128, 256, 0, stream>>>(hbuf, Wv_l, bv + l * 128, nullptr, vbuf, N);

        // attn (aliases qbuf)
        agg_kernel<<<rowBlocks, 256, 0, stream>>>(qbuf, kbuf, vbuf, offsets, esrc, qbuf, N);

        // h = h + attn @ Wo + bo   (in-place residual), then LN1 in-place
        gemm_kernel<128, 128, 2><<<g128, 256, 0, stream>>>(qbuf, Wo_l, bo + l * 128, hbuf, hbuf, N);
        ln_kernel<<<rowBlocks, 256, 0, stream>>>(hbuf, ln1w + l * 128, ln1b + l * 128, hbuf, N);

        // f1 = relu(hx @ Wf1 + bf1)  -> qbuf..kbuf (N x 256)
        gemm_kernel<128, 256, 1><<<g256, 256, 0, stream>>>(hbuf, Wf1_l, bf1 + l * 256, nullptr, qbuf, N);
        // h = hx + f1 @ Wf2 + bf2   (in-place residual)
        gemm_kernel<256, 128, 2><<<g128, 256, 0, stream>>>(qbuf, Wf2_l, bf2 + l * 128, hbuf, hbuf, N);
        // LN2 -> h (layer 0) or d_out (layer 1)
        float* lnout = (l == 1) ? out : hbuf;
        ln_kernel<<<rowBlocks, 256, 0, stream>>>(hbuf, ln2w + l * 128, ln2b + l * 128, lnout, N);
    }
}

// Round 2
// 657.687 us; speedup vs baseline: 1.5339x; 1.5339x over previous
//
#include <hip/hip_runtime.h>
#include <math.h>

static constexpr int N_NODES = 50000;
static constexpr int N_EDGES = 800000;
static constexpr int DMODEL  = 128;
static constexpr int MTILES  = N_NODES / 16;   // 3125 exactly

typedef __attribute__((ext_vector_type(8))) short short8;   // 8 bf16 (4 VGPRs)
typedef __attribute__((ext_vector_type(4))) float float4v;  // 4 fp32 acc

// fp32 -> bf16 RNE (bit trick), bf16 bits -> fp32
__device__ __forceinline__ unsigned short f2bf(float f) {
    unsigned u = __builtin_bit_cast(unsigned, f);
    u += 0x7fffu + ((u >> 16) & 1u);
    return (unsigned short)(u >> 16);
}
__device__ __forceinline__ float bf2f(unsigned short b) {
    unsigned u = ((unsigned)b) << 16;
    return __builtin_bit_cast(float, u);
}

// ---------------------------------------------------------------------------
// Weight prep: fp32 [K][N] row-major -> bf16 MFMA B-fragment order.
// For 16x16x32: lane holds B[k=quad*8+j][n=lane&15]; frag-ordered layout:
//   idx = (nt*ksteps + s)*512 + quad*128 + c*8 + j   (nt=n>>4, c=n&15, s=k>>5)
// so a wave's frag (nt,s) is 64 lanes x 16B contiguous.
// ---------------------------------------------------------------------------
struct PrepSeg { const float* src; int K; int N; int dstOff; };
struct PrepArgs { PrepSeg seg[13]; };

__global__ void prep_kernel(PrepArgs pa, unsigned short* wf)
{
    PrepSeg sg = pa.seg[blockIdx.y];
    int e = blockIdx.x * 256 + threadIdx.x;
    int total = sg.K * sg.N;
    if (e >= total) return;
    int n = e % sg.N;
    int k = e / sg.N;
    int ks = sg.K >> 5;
    int nt = n >> 4, c = n & 15, s = k >> 5, q = (k >> 3) & 3, jj = k & 7;
    int di = sg.dstOff + (nt * ks + s) * 512 + q * 128 + c * 8 + jj;
    wf[di] = f2bf(sg.src[e]);
}

// ---------------------------------------------------------------------------
// LDS-free MFMA GEMM: C[M,N] = A[M,K] @ W[K,N] (+bias)(+res)(relu)
// Wave = one 16-row m-tile x NT*16 cols; B-frags live in VGPRs (loaded once
// per wave from frag-ordered global); A-frags loaded straight from global.
// EPI: 0=bias, 1=bias+relu, 2=bias+residual. WRF/WRB: write fp32 / bf16.
// res/Cf may alias (in-place residual) -> not restrict.
// ---------------------------------------------------------------------------
template<int KSTEPS, int NT, int EPI, bool AF32, bool WRF, bool WRB>
__global__ __launch_bounds__(256, 2)
void mfma_gemm(const void* __restrict__ Ap, const unsigned short* __restrict__ Wf,
               const float* __restrict__ bias, const float* res,
               float* Cf, unsigned short* Cb, int ldA, int ldC, int mtiles)
{
    const int lane = threadIdx.x & 63;
    const int c = lane & 15;
    const int q = lane >> 4;
    const int colBase = blockIdx.y * NT * 16;
    const unsigned short* Wfc = Wf + (size_t)blockIdx.y * NT * KSTEPS * 512;

    // B fragments: NT*KSTEPS*4 VGPRs (<=128)
    short8 bfrag[NT][KSTEPS];
#pragma unroll
    for (int nt = 0; nt < NT; ++nt)
#pragma unroll
        for (int s = 0; s < KSTEPS; ++s)
            bfrag[nt][s] = *(const short8*)(Wfc + (nt * KSTEPS + s) * 512 + lane * 8);

    float bb[NT];
#pragma unroll
    for (int nt = 0; nt < NT; ++nt)
        bb[nt] = bias ? bias[colBase + nt * 16 + c] : 0.f;

    const int wid = blockIdx.x * 4 + (threadIdx.x >> 6);
    const int nw  = gridDim.x * 4;

    for (int mt = wid; mt < mtiles; mt += nw) {
        const int row0 = mt * 16;
        short8 afrag[KSTEPS];
        if (AF32) {
            const float* A32 = (const float*)Ap;
#pragma unroll
            for (int s = 0; s < KSTEPS; ++s) {
                const float4* p = (const float4*)(A32 + (size_t)(row0 + c) * ldA + s * 32 + q * 8);
                float4 x0 = p[0], x1 = p[1];
                short8 a;
                a[0] = (short)f2bf(x0.x); a[1] = (short)f2bf(x0.y);
                a[2] = (short)f2bf(x0.z); a[3] = (short)f2bf(x0.w);
                a[4] = (short)f2bf(x1.x); a[5] = (short)f2bf(x1.y);
                a[6] = (short)f2bf(x1.z); a[7] = (short)f2bf(x1.w);
                afrag[s] = a;
            }
        } else {
            const unsigned short* Ab = (const unsigned short*)Ap;
#pragma unroll
            for (int s = 0; s < KSTEPS; ++s)
                afrag[s] = *(const short8*)(Ab + (size_t)(row0 + c) * ldA + s * 32 + q * 8);
        }

        float4v acc[NT];
#pragma unroll
        for (int nt = 0; nt < NT; ++nt) acc[nt] = (float4v)0.f;
#pragma unroll
        for (int s = 0; s < KSTEPS; ++s)
#pragma unroll
            for (int nt = 0; nt < NT; ++nt)
                acc[nt] = __builtin_amdgcn_mfma_f32_16x16x32_bf16(afrag[s], bfrag[nt][s], acc[nt], 0, 0, 0);

        // epilogue: C row = row0 + q*4 + r, col = colBase + nt*16 + c
#pragma unroll
        for (int nt = 0; nt < NT; ++nt) {
            const int col = colBase + nt * 16 + c;
#pragma unroll
            for (int r = 0; r < 4; ++r) {
                const int grow = row0 + q * 4 + r;
                float v = acc[nt][r] + bb[nt];
                if (EPI == 2) v += res[(size_t)grow * ldC + col];
                if (EPI == 1) v = fmaxf(v, 0.f);
                if (WRF) Cf[(size_t)grow * ldC + col] = v;
                if (WRB) Cb[(size_t)grow * ldC + col] = f2bf(v);
            }
        }
    }
}

// ---------------------------------------------------------------------------
// LayerNorm rows of [M,128] fp32; writes fp32 (+optional bf16 mirror).
// ---------------------------------------------------------------------------
__global__ __launch_bounds__(256)
void ln_kernel(const float* x, const float* __restrict__ w,
               const float* __restrict__ b, float* outf, unsigned short* outb, int M)
{
    int row  = (int)((blockIdx.x * 256 + threadIdx.x) >> 6);
    int lane = threadIdx.x & 63;
    if (row >= M) return;
    const float* xr = x + (size_t)row * 128;
    float x0 = xr[lane];
    float x1 = xr[lane + 64];
    float s  = x0 + x1;
    float ss = x0 * x0 + x1 * x1;
#pragma unroll
    for (int o = 1; o < 64; o <<= 1) {
        s  += __shfl_xor(s, o, 64);
        ss += __shfl_xor(ss, o, 64);
    }
    float m   = s * (1.0f / 128.0f);
    float var = ss * (1.0f / 128.0f) - m * m;
    float rs  = rsqrtf(var + 1e-5f);
    float o0 = (x0 - m) * rs * w[lane] + b[lane];
    float o1 = (x1 - m) * rs * w[lane + 64] + b[lane + 64];
    outf[(size_t)row * 128 + lane]      = o0;
    outf[(size_t)row * 128 + lane + 64] = o1;
    if (outb) {
        outb[(size_t)row * 128 + lane]      = f2bf(o0);
        outb[(size_t)row * 128 + lane + 64] = f2bf(o1);
    }
}

// ---------------------------------------------------------------------------
// CSR build: histogram -> scan -> scatter (offsets become segment ends).
// ---------------------------------------------------------------------------
__global__ void hist_kernel(const int* __restrict__ dst, int* counts, int E)
{
    int e = blockIdx.x * 256 + threadIdx.x;
    if (e < E) atomicAdd(&counts[dst[e]], 1);
}

__global__ __launch_bounds__(1024)
void scan1_kernel(const int* __restrict__ counts, int* offsets, int* blockSums, int N)
{
    __shared__ int sm[1024];
    int t = threadIdx.x;
    int i = blockIdx.x * 1024 + t;
    sm[t] = (i < N) ? counts[i] : 0;
    __syncthreads();
#pragma unroll
    for (int o = 1; o < 1024; o <<= 1) {
        int v = (t >= o) ? sm[t - o] : 0;
        __syncthreads();
        sm[t] += v;
        __syncthreads();
    }
    if (i < N) offsets[i + 1] = sm[t];
    if (t == 1023) blockSums[blockIdx.x] = sm[t];
}

__global__ void scan2_kernel(int* blockSums, int nb)
{
    int t = threadIdx.x;   // 64 threads = 1 wave
    int own = (t < nb) ? blockSums[t] : 0;
    int x = own;
#pragma unroll
    for (int o = 1; o < 64; o <<= 1) {
        int v = __shfl_up(x, o, 64);
        if (t >= o) x += v;
    }
    if (t < nb) blockSums[t] = x - own;
}

__global__ __launch_bounds__(1024)
void scan3_kernel(int* offsets, const int* __restrict__ blockSums, int N)
{
    int i = blockIdx.x * 1024 + threadIdx.x;
    if (i < N) offsets[i + 1] += blockSums[blockIdx.x];
    if (i == 0) offsets[0] = 0;
}

__global__ void scatter_kernel(const int* __restrict__ src, const int* __restrict__ dst,
                               int* offsets, int* esrc, int E)
{
    int e = blockIdx.x * 256 + threadIdx.x;
    if (e < E) {
        int d = dst[e];
        int pos = atomicAdd(&offsets[d], 1);
        esrc[pos] = src[e];
    }
}

// ---------------------------------------------------------------------------
// Attention aggregation, bf16 Q/K/V in, bf16 attn out. One wave per dst node;
// lane covers dims {2l,2l+1}; 8-lane shuffle reduce per head.
// attn may alias q (row n read+written only by wave n).
// ---------------------------------------------------------------------------
__global__ __launch_bounds__(256)
void agg_kernel(const unsigned short* qv, const unsigned short* __restrict__ kv,
                const unsigned short* __restrict__ vv, const int* __restrict__ offsets,
                const int* __restrict__ esrc, unsigned short* attn, int n_nodes)
{
    int w    = (int)((blockIdx.x * 256 + threadIdx.x) >> 6);
    int lane = threadIdx.x & 63;
    if (w >= n_nodes) return;
    unsigned qb = *(const unsigned*)(qv + (size_t)w * 128 + lane * 2);
    float qx = bf2f((unsigned short)(qb & 0xffff));
    float qy = bf2f((unsigned short)(qb >> 16));
    int beg = (w == 0) ? 0 : offsets[w - 1];
    int end = offsets[w];
    float accx = 0.f, accy = 0.f, z = 0.f;
    for (int e = beg; e < end; ++e) {
        int s = esrc[e];
        unsigned kb = *(const unsigned*)(kv + (size_t)s * 128 + lane * 2);
        unsigned vb = *(const unsigned*)(vv + (size_t)s * 128 + lane * 2);
        float kx = bf2f((unsigned short)(kb & 0xffff));
        float ky = bf2f((unsigned short)(kb >> 16));
        float vx = bf2f((unsigned short)(vb & 0xffff));
        float vy = bf2f((unsigned short)(vb >> 16));
        float p = kx * qx + ky * qy;
        p += __shfl_xor(p, 1, 8);
        p += __shfl_xor(p, 2, 8);
        p += __shfl_xor(p, 4, 8);
        p *= 0.25f;                          // 1/sqrt(16)
        p = fminf(fmaxf(p, -5.f), 5.f);
        float sv = __expf(p);
        accx = fmaf(sv, vx, accx);
        accy = fmaf(sv, vy, accy);
        z += sv;
    }
    float inv = 1.f / (z + 1e-6f);
    unsigned outw = (unsigned)f2bf(accx * inv) | ((unsigned)f2bf(accy * inv) << 16);
    *(unsigned*)(attn + (size_t)w * 128 + lane * 2) = outw;
}

// ---------------------------------------------------------------------------
extern "C" void kernel_launch(void* const* d_in, const int* in_sizes, int n_in,
                              void* d_out, int out_size, void* d_ws, size_t ws_size,
                              hipStream_t stream)
{
    const float* h_in  = (const float*)d_in[0];
    const int*   src   = (const int*)d_in[1];
    const int*   dst   = (const int*)d_in[2];
    const float* W_emb = (const float*)d_in[3];
    const float* Wq    = (const float*)d_in[4];
    const float* bq    = (const float*)d_in[5];
    const float* Wk    = (const float*)d_in[6];
    const float* bk    = (const float*)d_in[7];
    const float* Wv    = (const float*)d_in[8];
    const float* bv    = (const float*)d_in[9];
    const float* Wo    = (const float*)d_in[10];
    const float* bo    = (const float*)d_in[11];
    const float* ln1w  = (const float*)d_in[12];
    const float* ln1b  = (const float*)d_in[13];
    const float* Wf1   = (const float*)d_in[14];
    const float* bf1   = (const float*)d_in[15];
    const float* Wf2   = (const float*)d_in[16];
    const float* bf2   = (const float*)d_in[17];
    const float* ln2w  = (const float*)d_in[18];
    const float* ln2b  = (const float*)d_in[19];
    float* out = (float*)d_out;

    const int N = N_NODES, E = N_EDGES;
    const size_t NF = (size_t)N * DMODEL;   // 6.4M elems

    // workspace carve (~81 MB)
    float*          hbuf = (float*)d_ws;           // fp32 master h
    unsigned short* hbf  = (unsigned short*)(hbuf + NF);  // bf16 mirror of h
    unsigned short* qbuf = hbf + NF;               // q / attn (bf16)
    unsigned short* kbuf = qbuf + NF;              // k; later f1 spans kbuf..vbuf
    unsigned short* vbuf = kbuf + NF;              // v
    unsigned short* wf   = vbuf + NF;              // frag-ordered weights, 278528
    int* offsets   = (int*)(wf + 278528);          // N+1
    int* blockSums = offsets + (N + 1);            // 64
    int* counts    = blockSums + 64;               // N
    int* esrc      = counts + N;                   // E
    unsigned short* fbuf = kbuf;                   // [N][256] bf16 FFN hidden

    // weight fragment offsets (elements)
    const int EMB_O = 0, Q_O = 16384, K_O = 49152, V_O = 81920, O_O = 114688,
              F1_O = 147456, F2_O = 212992;

    const int edgeBlocks = (E + 255) / 256;
    const int scanBlocks = (N + 1023) / 1024;
    const int rowBlocks  = (N + 3) / 4;
    const int GX = 391;                            // GEMM grid.x (1564 waves)

    // ---- CSR build ----
    hipMemsetAsync(counts, 0, (size_t)N * sizeof(int), stream);
    hist_kernel<<<edgeBlocks, 256, 0, stream>>>(dst, counts, E);
    scan1_kernel<<<scanBlocks, 1024, 0, stream>>>(counts, offsets, blockSums, N);
    scan2_kernel<<<1, 64, 0, stream>>>(blockSums, scanBlocks);
    scan3_kernel<<<scanBlocks, 1024, 0, stream>>>(offsets, blockSums, N);
    scatter_kernel<<<edgeBlocks, 256, 0, stream>>>(src, dst, offsets, esrc, E);

    // ---- weight prep (all 13 matrices -> frag-ordered bf16) ----
    PrepArgs pa;
    pa.seg[0]  = {W_emb,          128, 128, EMB_O};
    pa.seg[1]  = {Wq,             128, 128, Q_O};
    pa.seg[2]  = {Wq + 16384,     128, 128, Q_O + 16384};
    pa.seg[3]  = {Wk,             128, 128, K_O};
    pa.seg[4]  = {Wk + 16384,     128, 128, K_O + 16384};
    pa.seg[5]  = {Wv,             128, 128, V_O};
    pa.seg[6]  = {Wv + 16384,     128, 128, V_O + 16384};
    pa.seg[7]  = {Wo,             128, 128, O_O};
    pa.seg[8]  = {Wo + 16384,     128, 128, O_O + 16384};
    pa.seg[9]  = {Wf1,            128, 256, F1_O};
    pa.seg[10] = {Wf1 + 32768,    128, 256, F1_O + 32768};
    pa.seg[11] = {Wf2,            256, 128, F2_O};
    pa.seg[12] = {Wf2 + 32768,    256, 128, F2_O + 32768};
    prep_kernel<<<dim3(128, 13), 256, 0, stream>>>(pa, wf);

    // ---- embedding: h = h_in @ W_emb (fp32 A, no bias) -> hbuf + hbf ----
    mfma_gemm<4, 8, 0, true, true, true><<<dim3(GX, 1), 256, 0, stream>>>(
        h_in, wf + EMB_O, nullptr, nullptr, hbuf, hbf, 128, 128, MTILES);

    for (int l = 0; l < 2; ++l) {
        // Q,K,V (bf16 out only)
        mfma_gemm<4, 8, 0, false, false, true><<<dim3(GX, 1), 256, 0, stream>>>(
            hbf, wf + Q_O + l * 16384, bq + l * 128, nullptr, nullptr, qbuf, 128, 128, MTILES);
        mfma_gemm<4, 8, 0, false, false, true><<<dim3(GX, 1), 256, 0, stream>>>(
            hbf, wf + K_O + l * 16384, bk + l * 128, nullptr, nullptr, kbuf, 128, 128, MTILES);
        mfma_gemm<4, 8, 0, false, false, true><<<dim3(GX, 1), 256, 0, stream>>>(
            hbf, wf + V_O + l * 16384, bv + l * 128, nullptr, nullptr, vbuf, 128, 128, MTILES);

        // attention aggregate (attn aliases qbuf)
        agg_kernel<<<rowBlocks, 256, 0, stream>>>(qbuf, kbuf, vbuf, offsets, esrc, qbuf, N);

        // h = h + attn @ Wo + bo (fp32, in-place residual)
        mfma_gemm<4, 8, 2, false, true, false><<<dim3(GX, 1), 256, 0, stream>>>(
            qbuf, wf + O_O + l * 16384, bo + l * 128, hbuf, hbuf, nullptr, 128, 128, MTILES);
        // LN1 -> hbuf fp32 + hbf bf16
        ln_kernel<<<rowBlocks, 256, 0, stream>>>(hbuf, ln1w + l * 128, ln1b + l * 128, hbuf, hbf, N);

        // f1 = relu(hx @ Wf1 + bf1) -> bf16 [N,256]
        mfma_gemm<4, 8, 1, false, false, true><<<dim3(GX, 2), 256, 0, stream>>>(
            hbf, wf + F1_O + l * 32768, bf1 + l * 256, nullptr, nullptr, fbuf, 128, 256, MTILES);
        // h = hx + f1 @ Wf2 + bf2 (fp32, in-place residual)
        mfma_gemm<8, 4, 2, false, true, false><<<dim3(GX, 2), 256, 0, stream>>>(
            fbuf, wf + F2_O + l * 32768, bf2 + l * 128, hbuf, hbuf, nullptr, 256, 128, MTILES);

        // LN2 -> hbuf+hbf (layer 0) or d_out fp32 (layer 1)
        if (l == 0)
            ln_kernel<<<rowBlocks, 256, 0, stream>>>(hbuf, ln2w, ln2b, hbuf, hbf, N);
        else
            ln_kernel<<<rowBlocks, 256, 0, stream>>>(hbuf, ln2w + 128, ln2b + 128, out, nullptr, N);
    }
}

// Round 3
// 497.372 us; speedup vs baseline: 2.0284x; 1.3223x over previous
//
#include <hip/hip_runtime.h>
#include <math.h>

static constexpr int N_NODES = 50000;
static constexpr int N_EDGES = 800000;
static constexpr int DMODEL  = 128;
static constexpr int MTILES  = N_NODES / 16;   // 3125 exactly

typedef __attribute__((ext_vector_type(8))) short short8;   // 8 bf16 (4 VGPRs)
typedef __attribute__((ext_vector_type(4))) float float4v;  // 4 fp32 acc

__device__ __forceinline__ unsigned short f2bf(float f) {
    unsigned u = __builtin_bit_cast(unsigned, f);
    u += 0x7fffu + ((u >> 16) & 1u);
    return (unsigned short)(u >> 16);
}
__device__ __forceinline__ float bf2f(unsigned short b) {
    unsigned u = ((unsigned)b) << 16;
    return __builtin_bit_cast(float, u);
}

// ---------------------------------------------------------------------------
// Weight prep: fp32 [K][N] row-major -> bf16 MFMA B-fragment order.
//   idx = (nt*ksteps + s)*512 + quad*128 + c*8 + j   (nt=n>>4, c=n&15, s=k>>5)
// ---------------------------------------------------------------------------
struct PrepSeg { const float* src; int K; int N; int dstOff; };
struct PrepArgs { PrepSeg seg[13]; };

__global__ void prep_kernel(PrepArgs pa, unsigned short* wf)
{
    PrepSeg sg = pa.seg[blockIdx.y];
    int e = blockIdx.x * 256 + threadIdx.x;
    int total = sg.K * sg.N;
    if (e >= total) return;
    int n = e % sg.N;
    int k = e / sg.N;
    int ks = sg.K >> 5;
    int nt = n >> 4, c = n & 15, s = k >> 5, q = (k >> 3) & 3, jj = k & 7;
    int di = sg.dstOff + (nt * ks + s) * 512 + q * 128 + c * 8 + jj;
    wf[di] = f2bf(sg.src[e]);
}

// ---------------------------------------------------------------------------
// LDS-free MFMA GEMM body. Wave = 16-row m-tile x NT*16 cols; B-frags in
// VGPRs (loaded once per wave). EPI: 0=bias, 1=bias+relu, 2=bias+residual,
// 3=bias+residual+LayerNorm (requires NT*16==128, colBase==0).
// ---------------------------------------------------------------------------
template<int KSTEPS, int NT, int EPI, bool AF32, bool WRF, bool WRB>
__device__ __forceinline__ void gemm_body(
    const void* __restrict__ Ap, const unsigned short* __restrict__ Wfc,
    const float* __restrict__ bias, const float* res,
    float* Cf, unsigned short* Cb,
    const float* __restrict__ lnw, const float* __restrict__ lnb,
    int ldA, int ldC, int mtiles, int colBase)
{
    const int lane = threadIdx.x & 63;
    const int c = lane & 15;
    const int q = lane >> 4;

    short8 bfrag[NT][KSTEPS];
#pragma unroll
    for (int nt = 0; nt < NT; ++nt)
#pragma unroll
        for (int s = 0; s < KSTEPS; ++s)
            bfrag[nt][s] = *(const short8*)(Wfc + (nt * KSTEPS + s) * 512 + lane * 8);

    float bb[NT];
#pragma unroll
    for (int nt = 0; nt < NT; ++nt)
        bb[nt] = bias ? bias[colBase + nt * 16 + c] : 0.f;

    float lw[NT], lb[NT];
    if (EPI == 3) {
#pragma unroll
        for (int nt = 0; nt < NT; ++nt) {
            lw[nt] = lnw[nt * 16 + c];
            lb[nt] = lnb[nt * 16 + c];
        }
    }

    const int wid = blockIdx.x * 4 + (threadIdx.x >> 6);
    const int nw  = gridDim.x * 4;

    for (int mt = wid; mt < mtiles; mt += nw) {
        const int row0 = mt * 16;
        short8 afrag[KSTEPS];
        if (AF32) {
            const float* A32 = (const float*)Ap;
#pragma unroll
            for (int s = 0; s < KSTEPS; ++s) {
                const float4* p = (const float4*)(A32 + (size_t)(row0 + c) * ldA + s * 32 + q * 8);
                float4 x0 = p[0], x1 = p[1];
                short8 a;
                a[0] = (short)f2bf(x0.x); a[1] = (short)f2bf(x0.y);
                a[2] = (short)f2bf(x0.z); a[3] = (short)f2bf(x0.w);
                a[4] = (short)f2bf(x1.x); a[5] = (short)f2bf(x1.y);
                a[6] = (short)f2bf(x1.z); a[7] = (short)f2bf(x1.w);
                afrag[s] = a;
            }
        } else {
            const unsigned short* Ab = (const unsigned short*)Ap;
#pragma unroll
            for (int s = 0; s < KSTEPS; ++s)
                afrag[s] = *(const short8*)(Ab + (size_t)(row0 + c) * ldA + s * 32 + q * 8);
        }

        float4v acc[NT];
#pragma unroll
        for (int nt = 0; nt < NT; ++nt) acc[nt] = (float4v)0.f;
#pragma unroll
        for (int s = 0; s < KSTEPS; ++s)
#pragma unroll
            for (int nt = 0; nt < NT; ++nt)
                acc[nt] = __builtin_amdgcn_mfma_f32_16x16x32_bf16(afrag[s], bfrag[nt][s], acc[nt], 0, 0, 0);

        // epilogue: C row = row0 + q*4 + r, col = colBase + nt*16 + c
#pragma unroll
        for (int nt = 0; nt < NT; ++nt) {
            const int col = colBase + nt * 16 + c;
#pragma unroll
            for (int r = 0; r < 4; ++r) {
                const int grow = row0 + q * 4 + r;
                float v = acc[nt][r] + bb[nt];
                if (EPI == 2 || EPI == 3) v += res[(size_t)grow * ldC + col];
                if (EPI == 1) v = fmaxf(v, 0.f);
                acc[nt][r] = v;
            }
        }

        if (EPI == 3) {
            // full-row LayerNorm: reduce over 16 lanes of quad (cols) x NT regs
#pragma unroll
            for (int r = 0; r < 4; ++r) {
                float s = 0.f, ss = 0.f;
#pragma unroll
                for (int nt = 0; nt < NT; ++nt) {
                    float v = acc[nt][r];
                    s += v; ss = fmaf(v, v, ss);
                }
#pragma unroll
                for (int o = 1; o < 16; o <<= 1) {
                    s  += __shfl_xor(s, o, 64);
                    ss += __shfl_xor(ss, o, 64);
                }
                float m   = s * (1.0f / 128.0f);
                float var = ss * (1.0f / 128.0f) - m * m;
                float rs  = rsqrtf(var + 1e-5f);
                const int grow = row0 + q * 4 + r;
#pragma unroll
                for (int nt = 0; nt < NT; ++nt) {
                    float v = (acc[nt][r] - m) * rs * lw[nt] + lb[nt];
                    if (WRF) Cf[(size_t)grow * ldC + nt * 16 + c] = v;
                    if (WRB) Cb[(size_t)grow * ldC + nt * 16 + c] = f2bf(v);
                }
            }
        } else {
#pragma unroll
            for (int nt = 0; nt < NT; ++nt) {
                const int col = colBase + nt * 16 + c;
#pragma unroll
                for (int r = 0; r < 4; ++r) {
                    const int grow = row0 + q * 4 + r;
                    if (WRF) Cf[(size_t)grow * ldC + col] = acc[nt][r];
                    if (WRB) Cb[(size_t)grow * ldC + col] = f2bf(acc[nt][r]);
                }
            }
        }
    }
}

template<int KSTEPS, int NT, int EPI, bool AF32, bool WRF, bool WRB>
__global__ __launch_bounds__(256, 2)
void mfma_gemm(const void* __restrict__ Ap, const unsigned short* __restrict__ Wf,
               const float* __restrict__ bias, const float* res,
               float* Cf, unsigned short* Cb,
               const float* __restrict__ lnw, const float* __restrict__ lnb,
               int ldA, int ldC, int mtiles)
{
    const int colBase = blockIdx.y * NT * 16;
    const unsigned short* Wfc = Wf + (size_t)blockIdx.y * NT * KSTEPS * 512;
    gemm_body<KSTEPS, NT, EPI, AF32, WRF, WRB>(
        Ap, Wfc, bias, res, Cf, Cb, lnw, lnb, ldA, ldC, mtiles, colBase);
}

// Q/K/V fused: blockIdx.y in {0,1,2} selects weight block, bias, output.
struct QkvPtrs { const float* bias[3]; unsigned short* out[3]; };

__global__ __launch_bounds__(256, 2)
void qkv_gemm(const unsigned short* __restrict__ A, const unsigned short* __restrict__ WfBase,
              QkvPtrs ptrs, int mtiles)
{
    const int sel = blockIdx.y;
    gemm_body<4, 8, 0, false, false, true>(
        A, WfBase + (size_t)sel * 32768, ptrs.bias[sel], nullptr,
        nullptr, ptrs.out[sel], nullptr, nullptr, 128, 128, mtiles, 0);
}

// ---------------------------------------------------------------------------
// LayerNorm rows of [M,128] fp32; writes fp32 (+optional bf16 mirror).
// ---------------------------------------------------------------------------
__global__ __launch_bounds__(256)
void ln_kernel(const float* x, const float* __restrict__ w,
               const float* __restrict__ b, float* outf, unsigned short* outb, int M)
{
    int row  = (int)((blockIdx.x * 256 + threadIdx.x) >> 6);
    int lane = threadIdx.x & 63;
    if (row >= M) return;
    const float* xr = x + (size_t)row * 128;
    float x0 = xr[lane];
    float x1 = xr[lane + 64];
    float s  = x0 + x1;
    float ss = x0 * x0 + x1 * x1;
#pragma unroll
    for (int o = 1; o < 64; o <<= 1) {
        s  += __shfl_xor(s, o, 64);
        ss += __shfl_xor(ss, o, 64);
    }
    float m   = s * (1.0f / 128.0f);
    float var = ss * (1.0f / 128.0f) - m * m;
    float rs  = rsqrtf(var + 1e-5f);
    float o0 = (x0 - m) * rs * w[lane] + b[lane];
    float o1 = (x1 - m) * rs * w[lane + 64] + b[lane + 64];
    outf[(size_t)row * 128 + lane]      = o0;
    outf[(size_t)row * 128 + lane + 64] = o1;
    if (outb) {
        outb[(size_t)row * 128 + lane]      = f2bf(o0);
        outb[(size_t)row * 128 + lane + 64] = f2bf(o1);
    }
}

// ---------------------------------------------------------------------------
// CSR build: histogram -> scan -> scatter (offsets become segment ends).
// ---------------------------------------------------------------------------
__global__ void hist_kernel(const int* __restrict__ dst, int* counts, int E)
{
    int e = blockIdx.x * 256 + threadIdx.x;
    if (e < E) atomicAdd(&counts[dst[e]], 1);
}

__global__ __launch_bounds__(1024)
void scan1_kernel(const int* __restrict__ counts, int* offsets, int* blockSums, int N)
{
    __shared__ int sm[1024];
    int t = threadIdx.x;
    int i = blockIdx.x * 1024 + t;
    sm[t] = (i < N) ? counts[i] : 0;
    __syncthreads();
#pragma unroll
    for (int o = 1; o < 1024; o <<= 1) {
        int v = (t >= o) ? sm[t - o] : 0;
        __syncthreads();
        sm[t] += v;
        __syncthreads();
    }
    if (i < N) offsets[i + 1] = sm[t];
    if (t == 1023) blockSums[blockIdx.x] = sm[t];
}

__global__ void scan2_kernel(int* blockSums, int nb)
{
    int t = threadIdx.x;
    int own = (t < nb) ? blockSums[t] : 0;
    int x = own;
#pragma unroll
    for (int o = 1; o < 64; o <<= 1) {
        int v = __shfl_up(x, o, 64);
        if (t >= o) x += v;
    }
    if (t < nb) blockSums[t] = x - own;
}

__global__ __launch_bounds__(1024)
void scan3_kernel(int* offsets, const int* __restrict__ blockSums, int N)
{
    int i = blockIdx.x * 1024 + threadIdx.x;
    if (i < N) offsets[i + 1] += blockSums[blockIdx.x];
    if (i == 0) offsets[0] = 0;
}

__global__ void scatter_kernel(const int* __restrict__ src, const int* __restrict__ dst,
                               int* offsets, int* esrc, int E)
{
    int e = blockIdx.x * 256 + threadIdx.x;
    if (e < E) {
        int d = dst[e];
        int pos = atomicAdd(&offsets[d], 1);
        esrc[pos] = src[e];
    }
}

// ---------------------------------------------------------------------------
// Attention aggregation, 4x unrolled: 4 edge indices + 8 K/V row gathers
// issued per iteration before any compute (tail edges duplicated, masked 0).
// One wave per dst node; lane covers dims {2l,2l+1}; 8-lane shuffle reduce.
// attn may alias q (row n read+written only by wave n).
// ---------------------------------------------------------------------------
__global__ __launch_bounds__(256)
void agg_kernel(const unsigned short* qv, const unsigned short* __restrict__ kv,
                const unsigned short* __restrict__ vv, const int* __restrict__ offsets,
                const int* __restrict__ esrc, unsigned short* attn, int n_nodes)
{
    int w    = (int)((blockIdx.x * 256 + threadIdx.x) >> 6);
    int lane = threadIdx.x & 63;
    if (w >= n_nodes) return;
    unsigned qb = *(const unsigned*)(qv + (size_t)w * 128 + lane * 2);
    float qx = bf2f((unsigned short)(qb & 0xffff));
    float qy = bf2f((unsigned short)(qb >> 16));
    int beg = (w == 0) ? 0 : offsets[w - 1];
    int end = offsets[w];
    float accx = 0.f, accy = 0.f, z = 0.f;

    for (int e = beg; e < end; e += 4) {
        int rem = end - e;
        int s0 = esrc[e];
        int s1 = esrc[rem > 1 ? e + 1 : e];
        int s2 = esrc[rem > 2 ? e + 2 : e];
        int s3 = esrc[rem > 3 ? e + 3 : e];
        unsigned kb0 = *(const unsigned*)(kv + (size_t)s0 * 128 + lane * 2);
        unsigned kb1 = *(const unsigned*)(kv + (size_t)s1 * 128 + lane * 2);
        unsigned kb2 = *(const unsigned*)(kv + (size_t)s2 * 128 + lane * 2);
        unsigned kb3 = *(const unsigned*)(kv + (size_t)s3 * 128 + lane * 2);
        unsigned vb0 = *(const unsigned*)(vv + (size_t)s0 * 128 + lane * 2);
        unsigned vb1 = *(const unsigned*)(vv + (size_t)s1 * 128 + lane * 2);
        unsigned vb2 = *(const unsigned*)(vv + (size_t)s2 * 128 + lane * 2);
        unsigned vb3 = *(const unsigned*)(vv + (size_t)s3 * 128 + lane * 2);

        float p0 = bf2f((unsigned short)(kb0 & 0xffff)) * qx + bf2f((unsigned short)(kb0 >> 16)) * qy;
        float p1 = bf2f((unsigned short)(kb1 & 0xffff)) * qx + bf2f((unsigned short)(kb1 >> 16)) * qy;
        float p2 = bf2f((unsigned short)(kb2 & 0xffff)) * qx + bf2f((unsigned short)(kb2 >> 16)) * qy;
        float p3 = bf2f((unsigned short)(kb3 & 0xffff)) * qx + bf2f((unsigned short)(kb3 >> 16)) * qy;
#pragma unroll
        for (int o = 1; o < 8; o <<= 1) {
            p0 += __shfl_xor(p0, o, 8);
            p1 += __shfl_xor(p1, o, 8);
            p2 += __shfl_xor(p2, o, 8);
            p3 += __shfl_xor(p3, o, 8);
        }
        float m1 = (rem > 1) ? 1.f : 0.f;
        float m2 = (rem > 2) ? 1.f : 0.f;
        float m3 = (rem > 3) ? 1.f : 0.f;
        float sv0 = __expf(fminf(fmaxf(p0 * 0.25f, -5.f), 5.f));
        float sv1 = __expf(fminf(fmaxf(p1 * 0.25f, -5.f), 5.f)) * m1;
        float sv2 = __expf(fminf(fmaxf(p2 * 0.25f, -5.f), 5.f)) * m2;
        float sv3 = __expf(fminf(fmaxf(p3 * 0.25f, -5.f), 5.f)) * m3;

        accx = fmaf(sv0, bf2f((unsigned short)(vb0 & 0xffff)), accx);
        accy = fmaf(sv0, bf2f((unsigned short)(vb0 >> 16)),    accy);
        accx = fmaf(sv1, bf2f((unsigned short)(vb1 & 0xffff)), accx);
        accy = fmaf(sv1, bf2f((unsigned short)(vb1 >> 16)),    accy);
        accx = fmaf(sv2, bf2f((unsigned short)(vb2 & 0xffff)), accx);
        accy = fmaf(sv2, bf2f((unsigned short)(vb2 >> 16)),    accy);
        accx = fmaf(sv3, bf2f((unsigned short)(vb3 & 0xffff)), accx);
        accy = fmaf(sv3, bf2f((unsigned short)(vb3 >> 16)),    accy);
        z += sv0 + sv1 + sv2 + sv3;
    }
    float inv = 1.f / (z + 1e-6f);
    unsigned outw = (unsigned)f2bf(accx * inv) | ((unsigned)f2bf(accy * inv) << 16);
    *(unsigned*)(attn + (size_t)w * 128 + lane * 2) = outw;
}

// ---------------------------------------------------------------------------
extern "C" void kernel_launch(void* const* d_in, const int* in_sizes, int n_in,
                              void* d_out, int out_size, void* d_ws, size_t ws_size,
                              hipStream_t stream)
{
    const float* h_in  = (const float*)d_in[0];
    const int*   src   = (const int*)d_in[1];
    const int*   dst   = (const int*)d_in[2];
    const float* W_emb = (const float*)d_in[3];
    const float* Wq    = (const float*)d_in[4];
    const float* bq    = (const float*)d_in[5];
    const float* Wk    = (const float*)d_in[6];
    const float* bk    = (const float*)d_in[7];
    const float* Wv    = (const float*)d_in[8];
    const float* bv    = (const float*)d_in[9];
    const float* Wo    = (const float*)d_in[10];
    const float* bo    = (const float*)d_in[11];
    const float* ln1w  = (const float*)d_in[12];
    const float* ln1b  = (const float*)d_in[13];
    const float* Wf1   = (const float*)d_in[14];
    const float* bf1   = (const float*)d_in[15];
    const float* Wf2   = (const float*)d_in[16];
    const float* bf2   = (const float*)d_in[17];
    const float* ln2w  = (const float*)d_in[18];
    const float* ln2b  = (const float*)d_in[19];
    float* out = (float*)d_out;

    const int N = N_NODES, E = N_EDGES;
    const size_t NF = (size_t)N * DMODEL;

    float*          hbuf = (float*)d_ws;
    unsigned short* hbf  = (unsigned short*)(hbuf + NF);
    unsigned short* qbuf = hbf + NF;
    unsigned short* kbuf = qbuf + NF;
    unsigned short* vbuf = kbuf + NF;
    unsigned short* wf   = vbuf + NF;
    int* offsets   = (int*)(wf + 278528);
    int* blockSums = offsets + (N + 1);
    int* counts    = blockSums + 64;
    int* esrc      = counts + N;
    unsigned short* fbuf = kbuf;   // [N][256] bf16 FFN hidden

    const int EMB_O = 0, Q_O = 16384, K_O = 49152, V_O = 81920, O_O = 114688,
              F1_O = 147456, F2_O = 212992;

    const int edgeBlocks = (E + 255) / 256;
    const int scanBlocks = (N + 1023) / 1024;
    const int rowBlocks  = (N + 3) / 4;
    const int GX = 391;

    // ---- CSR build ----
    hipMemsetAsync(counts, 0, (size_t)N * sizeof(int), stream);
    hist_kernel<<<edgeBlocks, 256, 0, stream>>>(dst, counts, E);
    scan1_kernel<<<scanBlocks, 1024, 0, stream>>>(counts, offsets, blockSums, N);
    scan2_kernel<<<1, 64, 0, stream>>>(blockSums, scanBlocks);
    scan3_kernel<<<scanBlocks, 1024, 0, stream>>>(offsets, blockSums, N);
    scatter_kernel<<<edgeBlocks, 256, 0, stream>>>(src, dst, offsets, esrc, E);

    // ---- weight prep ----
    PrepArgs pa;
    pa.seg[0]  = {W_emb,          128, 128, EMB_O};
    pa.seg[1]  = {Wq,             128, 128, Q_O};
    pa.seg[2]  = {Wq + 16384,     128, 128, Q_O + 16384};
    pa.seg[3]  = {Wk,             128, 128, K_O};
    pa.seg[4]  = {Wk + 16384,     128, 128, K_O + 16384};
    pa.seg[5]  = {Wv,             128, 128, V_O};
    pa.seg[6]  = {Wv + 16384,     128, 128, V_O + 16384};
    pa.seg[7]  = {Wo,             128, 128, O_O};
    pa.seg[8]  = {Wo + 16384,     128, 128, O_O + 16384};
    pa.seg[9]  = {Wf1,            128, 256, F1_O};
    pa.seg[10] = {Wf1 + 32768,    128, 256, F1_O + 32768};
    pa.seg[11] = {Wf2,            256, 128, F2_O};
    pa.seg[12] = {Wf2 + 32768,    256, 128, F2_O + 32768};
    prep_kernel<<<dim3(128, 13), 256, 0, stream>>>(pa, wf);

    // ---- embedding: h = h_in @ W_emb (fp32 A) -> hbuf + hbf ----
    mfma_gemm<4, 8, 0, true, true, true><<<dim3(GX, 1), 256, 0, stream>>>(
        h_in, wf + EMB_O, nullptr, nullptr, hbuf, hbf, nullptr, nullptr, 128, 128, MTILES);

    for (int l = 0; l < 2; ++l) {
        // Q,K,V in one dispatch
        QkvPtrs qp;
        qp.bias[0] = bq + l * 128; qp.bias[1] = bk + l * 128; qp.bias[2] = bv + l * 128;
        qp.out[0] = qbuf; qp.out[1] = kbuf; qp.out[2] = vbuf;
        qkv_gemm<<<dim3(GX, 3), 256, 0, stream>>>(hbf, wf + Q_O + l * 16384, qp, MTILES);

        // attention aggregate (attn aliases qbuf)
        agg_kernel<<<rowBlocks, 256, 0, stream>>>(qbuf, kbuf, vbuf, offsets, esrc, qbuf, N);

        // hx = LN1(h + attn @ Wo + bo)  [fused GEMM+residual+LN] -> hbuf + hbf
        mfma_gemm<4, 8, 3, false, true, true><<<dim3(GX, 1), 256, 0, stream>>>(
            qbuf, wf + O_O + l * 16384, bo + l * 128, hbuf, hbuf, hbf,
            ln1w + l * 128, ln1b + l * 128, 128, 128, MTILES);

        // f1 = relu(hx @ Wf1 + bf1) -> bf16 [N,256]
        mfma_gemm<4, 8, 1, false, false, true><<<dim3(GX, 2), 256, 0, stream>>>(
            hbf, wf + F1_O + l * 32768, bf1 + l * 256, nullptr, nullptr, fbuf,
            nullptr, nullptr, 128, 256, MTILES);
        // h = hx + f1 @ Wf2 + bf2 (fp32, in-place residual)
        mfma_gemm<8, 4, 2, false, true, false><<<dim3(GX, 2), 256, 0, stream>>>(
            fbuf, wf + F2_O + l * 32768, bf2 + l * 128, hbuf, hbuf, nullptr,
            nullptr, nullptr, 256, 128, MTILES);

        // LN2 -> hbuf+hbf (layer 0) or d_out fp32 (layer 1)
        if (l == 0)
            ln_kernel<<<rowBlocks, 256, 0, stream>>>(hbuf, ln2w, ln2b, hbuf, hbf, N);
        else
            ln_kernel<<<rowBlocks, 256, 0, stream>>>(hbuf, ln2w + 128, ln2b + 128, out, nullptr, N);
    }
}